// Round 6
// baseline (448.121 us; speedup 1.0000x reference)
//
#include <hip/hip_runtime.h>
#include <hip/hip_bf16.h>
#include <math.h>

#define HID 64
#define HEADS 4
#define LAYERS 4
#define NRBF 20
#define NG 256
#define CB 512     // HID*8 bf16 elems per z/hb row
#define HSTRIDE 68 // padded channel stride in LDS (bf16 elems)
#define CAPB 64    // per-dst edge bucket capacity (max deg ~37 for Poisson(16), N=20000)
#define TABN 8192  // edge-MLP distance table: [0,16], step 1/512
#define NATOM 100

typedef __attribute__((ext_vector_type(8))) short short8;
typedef __attribute__((ext_vector_type(4))) float floatx4;

__device__ __forceinline__ int gradeOf(int b){ return (b==0)?0:((b<4)?1:((b<7)?2:3)); }
__device__ __forceinline__ unsigned short f2bf(float f){
    __hip_bfloat16 h = __float2bfloat16(f);
    return *(unsigned short*)&h;
}
__device__ __forceinline__ float bflo(int u){ return __uint_as_float(((unsigned)u)<<16); }
__device__ __forceinline__ float bfhi(int u){ return __uint_as_float(((unsigned)u)&0xFFFF0000u); }
__device__ __forceinline__ int packbf2(float a, float b){
    return (int)f2bf(a) | ((int)f2bf(b)<<16);
}

struct P {
    const float *pos; const int *zidx; const int *ei; const int *batch;
    const float *atom_w, *inproj_w, *inproj_b, *ew1, *eb1, *ew2, *eb2;
    const float *proj_w, *proj_b, *a_src, *a_dst, *w_src, *w_dst;
    const float *ln_a, *silu_a, *silu_b, *ppw, *ppb, *pw1, *pb1, *pw2, *pb2;
    float *out;
    int *counts; float *possum; float *pcnt; float *gbuf;
    int *bucket;       // [N][CAPB] src node id per slot
    int *escb;         // [N][CAPB] 2x int: 4 bf16 edge scalars per slot (bucket-slot order)
    float *tab;
    unsigned short *WTbf; float *ppw0T; float *w1T; float *sbf;
    float *embT;       // [NATOM][64] atom -> input_proj scalar channel (bias folded)
    unsigned short *hb;    // bf16 node state (z-row layout); residual + proj input
    unsigned short *zA; unsigned short *zB;
    float *ssA; float *sdA; float *ssB; float *sdB;
    int N, E, Mtiles;
};

// ---------------- k1: weight prep | node_stats | distance table | atom-embed table ----------------
__global__ __launch_bounds__(256) void k1_kernel(P p){
    const int PREP_TOTAL = LAYERS*4*64*64 + 2*HID*HID + 2*LAYERS*HEADS; // 73760
    const int CP = (PREP_TOTAL+255)/256;
    const int CN = (p.N+255)/256;
    const int CT = (TABN+1+3)/4;
    int bid = blockIdx.x, t = threadIdx.x;
    if (bid < CP){
        int idx = bid*256 + t;
        const int szW = LAYERS*4*64*64;
        const int e2 = szW + HID*HID;
        const int e3 = e2 + HID*HID;
        if (idx < szW){
            p.WTbf[idx] = f2bf(p.proj_w[idx]);
        } else if (idx < e2){
            int r = idx - szW; int i = r/HID, o = r%HID;
            p.ppw0T[r] = p.ppw[o*HID + i];
        } else if (idx < e3){
            int r = idx - e2; int i = r/HID, o = r%HID;
            p.w1T[r] = p.pw1[o*HID + i];
        } else if (idx < e3 + 2*LAYERS*HEADS){
            int r = idx - e3;
            int hh = r & 3; int type = (r>>2)&1; int l = r>>3;
            const float* a = type ? p.a_dst : p.a_src;
            const float* w = type ? p.w_dst : p.w_src;
            float wh = w[l*16 + hh*4 + 0];
            float s = 0.f;
            for (int c=0;c<16;c++)
                s += a[l*512 + (hh*16+c)*8 + 0] * wh * p.proj_b[l*64 + hh*16 + c];
            p.sbf[r] = s;
        }
    } else if (bid < CP+CN){
        int n = (bid-CP)*256 + t;
        if (n < p.N){
            int g = p.batch[n];
            atomicAdd(&p.possum[g*3+0], p.pos[n*3+0]);
            atomicAdd(&p.possum[g*3+1], p.pos[n*3+1]);
            atomicAdd(&p.possum[g*3+2], p.pos[n*3+2]);
            atomicAdd(&p.pcnt[g], 1.0f);
        }
    } else if (bid < CP+CN+CT){
        // distance table: one wave per entry, lane = hidden channel
        int wv = t>>6, lane = t&63;
        int i = (bid-CP-CN)*4 + wv;
        if (i > TABN) return;
        float d = (float)i * (16.0f/TABN);
        float t0 = d * (19.0f/10.0f);
        float hv = p.eb1[lane];
        #pragma unroll
        for (int k=0;k<NRBF;k++){
            float a = t0 - (float)k;
            hv += __expf(-0.5f*a*a) * p.ew1[lane*NRBF+k];
        }
        float act = hv/(1.0f+__expf(-hv));
        float p0 = act*p.ew2[0*HID+lane];
        float p1 = act*p.ew2[1*HID+lane];
        float p2 = act*p.ew2[2*HID+lane];
        float p3 = act*p.ew2[3*HID+lane];
        #pragma unroll
        for (int off=1; off<64; off<<=1){
            p0 += __shfl_xor(p0,off,64);
            p1 += __shfl_xor(p1,off,64);
            p2 += __shfl_xor(p2,off,64);
            p3 += __shfl_xor(p3,off,64);
        }
        if (lane==0){
            *(float4*)&p.tab[(size_t)i*4] = make_float4(p0+p.eb2[0], p1+p.eb2[1],
                                                        p2+p.eb2[2], p3+p.eb2[3]);
        }
    } else {
        // atom embedding table: one wave per atom type; lane = out channel
        int wv = t>>6, lane = t&63;
        int za = (bid-CP-CN-CT)*4 + wv;
        if (za >= NATOM) return;
        float accv = p.inproj_b[lane];
        for (int i=0;i<HID;i++)
            accv += p.atom_w[(size_t)za*HID + i] * p.inproj_w[lane*65 + i];
        p.embT[(size_t)za*HID + lane] = accv;
    }
}

// ---------------- proj math body (A-frags supplied by caller) ----------------
__device__ __forceinline__ void proj_core(const P& p, int pl, int n0, int nt, int lane,
        const short8* afr, bool rows16,
        unsigned short* zout, float* ssout, float* sdout){
    const unsigned short* WTl = p.WTbf + (size_t)pl*4*64*64;
    const float* pbl = p.proj_b + pl*HID;
    const float* a_src_l = p.a_src + pl*512;
    const float* a_dst_l = p.a_dst + pl*512;
    const float* w_src_l = p.w_src + pl*16;
    const float* w_dst_l = p.w_dst + pl*16;
    const float* sb_l = p.sbf + pl*8;
    int m = lane&15, quad = lane>>4;
    int o = nt*16 + m;
    float cs[4][2][4];
    float pss[4], psd[4];
    #pragma unroll
    for (int r=0;r<4;r++){ pss[r]=0.f; psd[r]=0.f; }
    #pragma unroll
    for (int bp=0; bp<4; bp++){
        const int b0 = 2*bp, b1 = b0+1;
        const int g0 = gradeOf(b0), g1 = gradeOf(b1);
        const short8 w00 = *(const short8*)(WTl + (g0*64 + o)*64 + quad*8);
        const short8 w01 = *(const short8*)(WTl + (g0*64 + o)*64 + 32 + quad*8);
        short8 w10, w11;
        if (g1==g0){ w10 = w00; w11 = w01; }
        else {
            w10 = *(const short8*)(WTl + (g1*64 + o)*64 + quad*8);
            w11 = *(const short8*)(WTl + (g1*64 + o)*64 + 32 + quad*8);
        }
        floatx4 c0 = {0.f,0.f,0.f,0.f}, c1 = {0.f,0.f,0.f,0.f};
        c0 = __builtin_amdgcn_mfma_f32_16x16x32_bf16(afr[4*bp+0], w00, c0, 0,0,0);
        c0 = __builtin_amdgcn_mfma_f32_16x16x32_bf16(afr[4*bp+1], w01, c0, 0,0,0);
        c1 = __builtin_amdgcn_mfma_f32_16x16x32_bf16(afr[4*bp+2], w10, c1, 0,0,0);
        c1 = __builtin_amdgcn_mfma_f32_16x16x32_bf16(afr[4*bp+3], w11, c1, 0,0,0);
        float as0 = a_src_l[o*8+b0]*w_src_l[nt*4+g0];
        float as1 = a_src_l[o*8+b1]*w_src_l[nt*4+g1];
        float ad0 = a_dst_l[o*8+b0]*w_dst_l[nt*4+g0];
        float ad1 = a_dst_l[o*8+b1]*w_dst_l[nt*4+g1];
        float bias0 = (bp==0) ? pbl[o] : 0.0f;
        #pragma unroll
        for (int r=0;r<4;r++){
            float v0 = c0[r], v1 = c1[r];
            pss[r] += v0*as0 + v1*as1;
            psd[r] += v0*ad0 + v1*ad1;
            cs[bp][0][r] = v0 + bias0;
            cs[bp][1][r] = v1;
        }
    }
    #pragma unroll
    for (int r=0;r<4;r++){
        int row = quad*4 + r;
        bool rowok = rows16 ? true : (quad==0);
        int nn = n0 + (rows16 ? row : r);
        if (rowok && nn < p.N){
            unsigned short pk[8];
            #pragma unroll
            for (int bp=0;bp<4;bp++){
                pk[2*bp]   = f2bf(cs[bp][0][r]);
                pk[2*bp+1] = f2bf(cs[bp][1][r]);
            }
            *(int4*)(zout + (size_t)nn*CB + o*8) = *(int4*)pk;
        }
    }
    #pragma unroll
    for (int r=0;r<4;r++){
        float vs = pss[r], vd = psd[r];
        #pragma unroll
        for (int off=1; off<16; off<<=1){
            vs += __shfl_xor(vs, off, 64);
            vd += __shfl_xor(vd, off, 64);
        }
        int row = quad*4 + r;
        bool rowok = rows16 ? true : (quad==0);
        int nn = n0 + (rows16 ? row : r);
        if (m==0 && rowok && nn<p.N){
            ssout[nn*4+nt] = vs + sb_l[nt];
            sdout[nn*4+nt] = vd + sb_l[4+nt];
        }
    }
}

// ---------------- k2: edge-lerp+bucket | embed+proj_0 (independent block ranges) ----------------
__global__ __launch_bounds__(256) void k2_kernel(P p){
    __shared__ unsigned short hAl[8*16*HSTRIDE];
    int t = threadIdx.x, wv = t>>6, lane = t&63;
    if ((int)blockIdx.x >= p.Mtiles){
        int e = ((int)blockIdx.x - p.Mtiles)*256 + t;
        if (e >= p.E) return;
        int s = p.ei[e], d = p.ei[p.E+e];
        float dx = p.pos[s*3+0]-p.pos[d*3+0];
        float dy = p.pos[s*3+1]-p.pos[d*3+1];
        float dz = p.pos[s*3+2]-p.pos[d*3+2];
        float dist = sqrtf(dx*dx+dy*dy+dz*dz);
        float idxf = fminf(dist * ((float)TABN/16.0f), (float)(TABN-1));
        int i0 = (int)idxf;
        float fr = idxf - (float)i0;
        float4 f0 = *(const float4*)&p.tab[(size_t)i0*4];
        float4 f1 = *(const float4*)&p.tab[(size_t)(i0+1)*4];
        int slot = atomicAdd(&p.counts[d],1);
        if (slot < CAPB){
            p.bucket[(size_t)d*CAPB + slot] = s;                      // src id, slot order
            int2 epk = make_int2(
                packbf2(f0.x + (f1.x-f0.x)*fr, f0.y + (f1.y-f0.y)*fr),
                packbf2(f0.z + (f1.z-f0.z)*fr, f0.w + (f1.w-f0.w)*fr));
            *(int2*)&p.escb[((size_t)d*CAPB + slot)*2] = epk;         // bf16 x4, slot order
        }
        return;
    }
    int n0 = blockIdx.x*16;
    float wvv = p.inproj_w[lane*65 + 64];   // vec-channel weight: loop-invariant
    for (int k=0;k<4;k++){
        int m = wv*4 + k;
        int n = n0 + m;
        if (n < p.N){
            int zn = p.zidx[n];                                   // wave-uniform
            float acc = p.embT[(size_t)zn*HID + lane];            // precomputed embed (L2-hot)
            int g = p.batch[n];
            float cm = p.pcnt[g]; cm = cm>1.0f?cm:1.0f;
            float px = p.pos[n*3+0]-p.possum[g*3+0]/cm;
            float py = p.pos[n*3+1]-p.possum[g*3+1]/cm;
            float pz = p.pos[n*3+2]-p.possum[g*3+2]/cm;
            unsigned short pk[8];
            pk[0]=f2bf(acc); pk[1]=f2bf(wvv*px); pk[2]=f2bf(wvv*py); pk[3]=f2bf(wvv*pz);
            pk[4]=0; pk[5]=0; pk[6]=0; pk[7]=0;
            *(int4*)(p.hb + (size_t)n*CB + lane*8) = *(int4*)pk;
            #pragma unroll
            for (int b=0;b<8;b++) hAl[(b*16+m)*HSTRIDE + lane] = pk[b];
        } else {
            #pragma unroll
            for (int b=0;b<8;b++) hAl[(b*16+m)*HSTRIDE + lane] = 0;
        }
    }
    __syncthreads();
    int m = lane&15, quad = lane>>4;
    short8 afr[16];
    #pragma unroll
    for (int bp=0;bp<4;bp++){
        int b0=2*bp, b1=b0+1;
        afr[4*bp+0] = *(const short8*)(hAl + (b0*16+m)*HSTRIDE + quad*8);
        afr[4*bp+1] = *(const short8*)(hAl + (b0*16+m)*HSTRIDE + 32 + quad*8);
        afr[4*bp+2] = *(const short8*)(hAl + (b1*16+m)*HSTRIDE + quad*8);
        afr[4*bp+3] = *(const short8*)(hAl + (b1*16+m)*HSTRIDE + 32 + quad*8);
    }
    proj_core(p, 0, n0, wv, lane, afr, true, p.zA, p.ssA, p.sdA);
}

// ---------------- agg helpers ----------------
__device__ __forceinline__ void fmab8(const float* lwv, int h_id, int J,
                                      const int4* zv, float* acc, float& dn){
    #pragma unroll
    for (int i=0;i<8;i++){
        float w = lwv[(J+i)*4 + h_id];
        acc[0] += w*bflo(zv[i].x); acc[1] += w*bfhi(zv[i].x);
        acc[2] += w*bflo(zv[i].y); acc[3] += w*bfhi(zv[i].y);
        acc[4] += w*bflo(zv[i].z); acc[5] += w*bfhi(zv[i].z);
        acc[6] += w*bflo(zv[i].w); acc[7] += w*bfhi(zv[i].w);
        dn += w;
    }
}

// ---------------- agg_l: 1 wave = 1 node; batch-0 issued before softmax; bf16 residual ----------------
__global__ __launch_bounds__(256) void agg_kernel(P p, int l,
        const unsigned short* __restrict__ zin, const float* __restrict__ ssin,
        const float* __restrict__ sdin, int last){
    __shared__ float lw[4][256];
    int wv = threadIdx.x>>6, lane = threadIdx.x&63;
    int n = blockIdx.x*4 + wv;
    if (n >= p.N) return;
    float* lwv = lw[wv];
    // residual (bf16 hb row) issued early; consumed only in epilogue
    int4 hres = *((const int4*)(p.hb + (size_t)n*CB) + lane);
    float4 sdl = *(const float4*)&sdin[n*4];
    int deg = min(p.counts[n], CAPB);
    int h_id = lane>>4;
    const int* bs = p.bucket + (size_t)n*CAPB;
    int s = 0;
    float l0=-1e30f,l1=-1e30f,l2=-1e30f,l3=-1e30f;
    if (lane < deg){
        s = bs[lane];                                              // coalesced, slot order
        int2 ev = *((const int2*)p.escb + ((size_t)n*CAPB + lane)); // coalesced, bf16 x4
        float4 sv  = *(const float4*)&ssin[s*4];                   // 16B gather, L2-hot
        l0 = sv.x+sdl.x+bflo(ev.x); l0=(l0>=0.f)?l0:0.2f*l0;
        l1 = sv.y+sdl.y+bfhi(ev.x); l1=(l1>=0.f)?l1:0.2f*l1;
        l2 = sv.z+sdl.z+bflo(ev.y); l2=(l2>=0.f)?l2:0.2f*l2;
        l3 = sv.w+sdl.w+bfhi(ev.y); l3=(l3>=0.f)?l3:0.2f*l3;
    }
    int bc = (deg+7)>>3;
    int4 zv[8];
    // issue batch 0 BEFORE the softmax shuffle chain: loads depend only on s
    if (bc>0){
        #pragma unroll
        for (int i=0;i<8;i++){
            int sb = __builtin_amdgcn_readlane(s, i);
            zv[i] = *((const int4*)(zin + (size_t)(unsigned)sb*CB) + lane);
        }
    }
    float m0=l0,m1=l1,m2=l2,m3=l3;
    #pragma unroll
    for (int off=1; off<64; off<<=1){
        m0=fmaxf(m0,__shfl_xor(m0,off,64));
        m1=fmaxf(m1,__shfl_xor(m1,off,64));
        m2=fmaxf(m2,__shfl_xor(m2,off,64));
        m3=fmaxf(m3,__shfl_xor(m3,off,64));
    }
    // lanes >= deg: l = -1e30 -> exp(l-m) = 0 (deg>0)
    *(float4*)&lwv[lane*4] = make_float4(__expf(l0-m0),__expf(l1-m1),
                                         __expf(l2-m2),__expf(l3-m3));
    float acc[8];
    #pragma unroll
    for (int k=0;k<8;k++) acc[k]=0.f;
    float dn = 0.f;
    if (bc>0) fmab8(lwv, h_id, 0, zv, acc, dn);
    for (int j=8; j<bc*8; j+=8){
        #pragma unroll
        for (int i=0;i<8;i++){
            int sb = __builtin_amdgcn_readlane(s, j+i);
            zv[i] = *((const int4*)(zin + (size_t)(unsigned)sb*CB) + lane);
        }
        fmab8(lwv, h_id, j, zv, acc, dn);
    }
    float inv = 1.0f/(dn + 1e-16f);
    float x[8];
    #pragma unroll
    for (int k=0;k<8;k++) x[k] = acc[k]*inv;
    const float* silu_a_l = p.silu_a + l*HID*4;
    const float* silu_b_l = p.silu_b + l*HID*4;
    float4 sa = *(const float4*)&silu_a_l[lane*4];
    float4 sb = *(const float4*)&silu_b_l[lane*4];
    float n1 = x[1]*x[1]+x[2]*x[2]+x[3]*x[3];
    float n2 = x[4]*x[4]+x[5]*x[5]+x[6]*x[6];
    float n3 = x[7]*x[7];
    float g0 = 1.0f/(1.0f+__expf(-(sa.x*x[0]+sb.x)));
    float g1 = 1.0f/(1.0f+__expf(-(sa.y*n1+sb.y)));
    float g2 = 1.0f/(1.0f+__expf(-(sa.z*n2+sb.z)));
    float g3 = 1.0f/(1.0f+__expf(-(sa.w*n3+sb.w)));
    float val[8];
    val[0]=g0*x[0]+bflo(hres.x); val[1]=g1*x[1]+bfhi(hres.x);
    val[2]=g1*x[2]+bflo(hres.y); val[3]=g1*x[3]+bfhi(hres.y);
    val[4]=g2*x[4]+bflo(hres.z); val[5]=g2*x[5]+bfhi(hres.z);
    val[6]=g2*x[6]+bflo(hres.w); val[7]=g3*x[7]+bfhi(hres.w);
    float ssq=0.f;
    #pragma unroll
    for (int k=0;k<8;k++) ssq += val[k]*val[k];
    float nr = sqrtf(ssq);
    #pragma unroll
    for (int off=1; off<64; off<<=1) nr += __shfl_xor(nr, off, 64);
    float mean = nr*(1.0f/64.0f) + 1e-6f;
    float scale = p.ln_a[l*HID + lane]/mean;
    float outv[8];
    #pragma unroll
    for (int k=0;k<8;k++) outv[k] = scale*val[k];
    if (!last){
        unsigned short pk[8];
        #pragma unroll
        for (int k=0;k<8;k++) pk[k] = f2bf(outv[k]);
        *(int4*)(p.hb + (size_t)n*CB + lane*8) = *(int4*)pk;   // bf16 state for proj + residual
    } else {
        // prepool is linear: accumulate scalar-blade sum per graph; matvec deferred to final
        atomicAdd(&p.gbuf[p.batch[n]*HID + lane], outv[0]);
    }
}

// ---------------- proj_pl: dense MFMA tiles over hb (bf16), 32 nodes/block -> z, ss, sd ----------------
__global__ __launch_bounds__(512) void proj_kernel(P p, int pl,
        unsigned short* zout, float* ssout, float* sdout){
    __shared__ unsigned short hAl[2][8*16*HSTRIDE];
    int t = threadIdx.x, wv = t>>6, lane = t&63;
    int nb = blockIdx.x*32;
    for (int k=0;k<4;k++){
        int m2 = wv*4 + k;              // row 0..31
        int tile = m2>>4, mr = m2&15;
        int n = nb + m2;
        if (n < p.N){
            int4 hv = *((const int4*)(p.hb + (size_t)n*CB) + lane);  // 16B: 8 bf16 blades of chan=lane
            unsigned short* pk = (unsigned short*)&hv;
            #pragma unroll
            for (int b=0;b<8;b++) hAl[tile][(b*16+mr)*HSTRIDE + lane] = pk[b];
        } else {
            #pragma unroll
            for (int b=0;b<8;b++) hAl[tile][(b*16+mr)*HSTRIDE + lane] = 0;
        }
    }
    __syncthreads();
    int tile = wv>>2, nt = wv&3;
    int n0 = nb + tile*16;
    const unsigned short* hT = hAl[tile];
    int m = lane&15, quad = lane>>4;
    short8 afr[16];
    #pragma unroll
    for (int bp=0;bp<4;bp++){
        int b0=2*bp, b1=b0+1;
        afr[4*bp+0] = *(const short8*)(hT + (b0*16+m)*HSTRIDE + quad*8);
        afr[4*bp+1] = *(const short8*)(hT + (b0*16+m)*HSTRIDE + 32 + quad*8);
        afr[4*bp+2] = *(const short8*)(hT + (b1*16+m)*HSTRIDE + quad*8);
        afr[4*bp+3] = *(const short8*)(hT + (b1*16+m)*HSTRIDE + 32 + quad*8);
    }
    proj_core(p, pl, n0, nt, lane, afr, true, zout, ssout, sdout);
}

// ---------------- final readout: gsc = cnt*ppb + W0^T gsum; out = MLP(gsc) ----------------
__global__ void final_kernel(P p){
    int gid = blockIdx.x; int o = threadIdx.x;  // 64 threads = 1 wave
    float gs = p.gbuf[gid*HID + o];             // sum of scalar-blade x0 over graph nodes
    float cnt = p.pcnt[gid];
    float gsc = cnt * p.ppb[o];
    for (int i=0;i<HID;i++) gsc += __shfl(gs, i, 64) * p.ppw0T[i*HID + o];
    float a = p.pb1[o];
    for (int i=0;i<HID;i++) a += __shfl(gsc, i, 64) * p.w1T[i*HID + o];
    float act = a/(1.0f+__expf(-a));
    float pv = act * p.pw2[o];
    #pragma unroll
    for (int off=1; off<64; off<<=1) pv += __shfl_xor(pv, off, 64);
    if (o==0) p.out[gid] = pv + p.pb2[0];
}

extern "C" void kernel_launch(void* const* d_in, const int* in_sizes, int n_in,
                              void* d_out, int out_size, void* d_ws, size_t ws_size,
                              hipStream_t stream) {
    P p;
    p.pos      = (const float*)d_in[0];
    p.zidx     = (const int*)  d_in[1];
    p.ei       = (const int*)  d_in[2];
    p.batch    = (const int*)  d_in[3];
    p.atom_w   = (const float*)d_in[4];
    p.inproj_w = (const float*)d_in[5];
    p.inproj_b = (const float*)d_in[6];
    p.ew1      = (const float*)d_in[7];
    p.eb1      = (const float*)d_in[8];
    p.ew2      = (const float*)d_in[9];
    p.eb2      = (const float*)d_in[10];
    p.proj_w   = (const float*)d_in[11];
    p.proj_b   = (const float*)d_in[12];
    p.a_src    = (const float*)d_in[13];
    p.a_dst    = (const float*)d_in[14];
    p.w_src    = (const float*)d_in[15];
    p.w_dst    = (const float*)d_in[16];
    p.ln_a     = (const float*)d_in[17];
    p.silu_a   = (const float*)d_in[18];
    p.silu_b   = (const float*)d_in[19];
    p.ppw      = (const float*)d_in[20];
    p.ppb      = (const float*)d_in[21];
    p.pw1      = (const float*)d_in[22];
    p.pb1      = (const float*)d_in[23];
    p.pw2      = (const float*)d_in[24];
    p.pb2      = (const float*)d_in[25];
    p.out = (float*)d_out;

    const int N = in_sizes[0]/3;
    const int E = in_sizes[2]/2;
    p.N = N; p.E = E; p.Mtiles = (N+15)/16;

    float* wsf = (float*)d_ws;
    size_t off = 0;
    auto alloc = [&](size_t nelem){ size_t r = off; off += (nelem + 63) & ~(size_t)63; return r; };
    size_t o_counts = alloc(N);          // int
    size_t o_possum = alloc(NG*3);
    size_t o_pcnt   = alloc(NG);
    size_t o_g      = alloc(NG*HID);
    size_t zero_end = off;
    size_t o_bucket = alloc((size_t)N*CAPB);          // int (src ids)
    size_t o_escb   = alloc((size_t)N*CAPB*2);        // int2 per slot (4 bf16)
    size_t o_tab    = alloc((size_t)(TABN+2)*4);
    size_t o_ssA    = alloc((size_t)N*4);
    size_t o_sdA    = alloc((size_t)N*4);
    size_t o_ssB    = alloc((size_t)N*4);
    size_t o_sdB    = alloc((size_t)N*4);
    size_t o_WTbf   = alloc((size_t)LAYERS*4*64*64/2);   // ushort
    size_t o_ppw0T  = alloc(HID*HID);
    size_t o_w1T    = alloc(HID*HID);
    size_t o_sbf    = alloc(2*LAYERS*HEADS);
    size_t o_embT   = alloc((size_t)NATOM*HID);
    size_t o_hb     = alloc((size_t)N*CB/2);             // ushort (bf16 node state)
    size_t o_zA     = alloc((size_t)N*CB/2);             // ushort
    size_t o_zB     = alloc((size_t)N*CB/2);             // ushort

    p.counts = (int*)(wsf + o_counts);
    p.possum = wsf + o_possum;
    p.pcnt   = wsf + o_pcnt;
    p.gbuf   = wsf + o_g;
    p.bucket = (int*)(wsf + o_bucket);
    p.escb   = (int*)(wsf + o_escb);
    p.tab    = wsf + o_tab;
    p.ssA    = wsf + o_ssA;
    p.sdA    = wsf + o_sdA;
    p.ssB    = wsf + o_ssB;
    p.sdB    = wsf + o_sdB;
    p.WTbf   = (unsigned short*)(wsf + o_WTbf);
    p.ppw0T  = wsf + o_ppw0T;
    p.w1T    = wsf + o_w1T;
    p.sbf    = wsf + o_sbf;
    p.embT   = wsf + o_embT;
    p.hb     = (unsigned short*)(wsf + o_hb);
    p.zA     = (unsigned short*)(wsf + o_zA);
    p.zB     = (unsigned short*)(wsf + o_zB);

    hipMemsetAsync(wsf, 0, zero_end*sizeof(float), stream);

    const int PREP_TOTAL = LAYERS*4*64*64 + 2*HID*HID + 2*LAYERS*HEADS;
    const int CP = (PREP_TOTAL+255)/256;
    const int CN = (N+255)/256;
    const int CE = (E+255)/256;
    const int CT = (TABN+1+3)/4;
    const int CEMB = (NATOM+3)/4;

    k1_kernel<<<CP+CN+CT+CEMB, 256, 0, stream>>>(p);
    k2_kernel<<<p.Mtiles + CE, 256, 0, stream>>>(p);    // -> escb/bucket | zA, ssA, sdA, hb

    const int AG = (N+3)/4;
    const int PG = (N+31)/32;
    agg_kernel <<<AG, 256, 0, stream>>>(p, 0, p.zA, p.ssA, p.sdA, 0);
    proj_kernel<<<PG, 512, 0, stream>>>(p, 1, p.zB, p.ssB, p.sdB);
    agg_kernel <<<AG, 256, 0, stream>>>(p, 1, p.zB, p.ssB, p.sdB, 0);
    proj_kernel<<<PG, 512, 0, stream>>>(p, 2, p.zA, p.ssA, p.sdA);
    agg_kernel <<<AG, 256, 0, stream>>>(p, 2, p.zA, p.ssA, p.sdA, 0);
    proj_kernel<<<PG, 512, 0, stream>>>(p, 3, p.zB, p.ssB, p.sdB);
    agg_kernel <<<AG, 256, 0, stream>>>(p, 3, p.zB, p.ssB, p.sdB, 1);

    final_kernel<<<NG, 64, 0, stream>>>(p);
}

// Round 7
// 408.170 us; speedup vs baseline: 1.0979x; 1.0979x over previous
//
#include <hip/hip_runtime.h>
#include <hip/hip_bf16.h>
#include <math.h>

#define HID 64
#define HEADS 4
#define LAYERS 4
#define NRBF 20
#define NG 256
#define CB 512     // HID*8 bf16 elems per z/hb row
#define HSTRIDE 68 // padded channel stride in LDS (bf16 elems)
#define CAPB 64    // per-dst edge bucket capacity (max deg ~37 for Poisson(16), N=20000)
#define TABN 8192  // edge-MLP distance table: [0,16], step 1/512
#define NATOM 100

typedef __attribute__((ext_vector_type(8))) short short8;
typedef __attribute__((ext_vector_type(4))) float floatx4;

__device__ __forceinline__ int gradeOf(int b){ return (b==0)?0:((b<4)?1:((b<7)?2:3)); }
__device__ __forceinline__ unsigned short f2bf(float f){
    __hip_bfloat16 h = __float2bfloat16(f);
    return *(unsigned short*)&h;
}
__device__ __forceinline__ float bflo(int u){ return __uint_as_float(((unsigned)u)<<16); }
__device__ __forceinline__ float bfhi(int u){ return __uint_as_float(((unsigned)u)&0xFFFF0000u); }
__device__ __forceinline__ int packbf2(float a, float b){
    return (int)f2bf(a) | ((int)f2bf(b)<<16);
}

struct P {
    const float *pos; const int *zidx; const int *ei; const int *batch;
    const float *atom_w, *inproj_w, *inproj_b, *ew1, *eb1, *ew2, *eb2;
    const float *proj_w, *proj_b, *a_src, *a_dst, *w_src, *w_dst;
    const float *ln_a, *silu_a, *silu_b, *ppw, *ppb, *pw1, *pb1, *pw2, *pb2;
    float *out;
    int *counts; float *possum; float *pcnt; float *gbuf;
    int *bucket;       // [N][CAPB] src node id per slot
    int *escb;         // [N][CAPB] 2x int: 4 bf16 edge scalars per slot (bucket-slot order)
    float *tab;
    unsigned short *WTbf; float *ppw0T; float *w1T; float *sbf;
    float *embT;       // [NATOM][64] atom -> input_proj scalar channel (bias folded)
    unsigned short *hb;    // bf16 node state (z-row layout); residual + proj input
    unsigned short *zA; unsigned short *zB;
    float *ssA; float *sdA; float *ssB; float *sdB;
    int N, E, Mtiles;
};

// ---------------- k1: weight prep | per-graph stats (no atomics) | distance table | atom-embed ----------------
__global__ __launch_bounds__(256) void k1_kernel(P p){
    const int PREP_TOTAL = LAYERS*4*64*64 + 2*HID*HID + 2*LAYERS*HEADS; // 73760
    const int CP = (PREP_TOTAL+255)/256;
    const int CG = NG/4;                 // 64 blocks: one wave per graph
    const int CT = (TABN+1+3)/4;
    int bid = blockIdx.x, t = threadIdx.x;
    if (bid < CP){
        int idx = bid*256 + t;
        const int szW = LAYERS*4*64*64;
        const int e2 = szW + HID*HID;
        const int e3 = e2 + HID*HID;
        if (idx < szW){
            p.WTbf[idx] = f2bf(p.proj_w[idx]);
        } else if (idx < e2){
            int r = idx - szW; int i = r/HID, o = r%HID;
            p.ppw0T[r] = p.ppw[o*HID + i];
        } else if (idx < e3){
            int r = idx - e2; int i = r/HID, o = r%HID;
            p.w1T[r] = p.pw1[o*HID + i];
        } else if (idx < e3 + 2*LAYERS*HEADS){
            int r = idx - e3;
            int hh = r & 3; int type = (r>>2)&1; int l = r>>3;
            const float* a = type ? p.a_dst : p.a_src;
            const float* w = type ? p.w_dst : p.w_src;
            float wh = w[l*16 + hh*4 + 0];
            float s = 0.f;
            for (int c=0;c<16;c++)
                s += a[l*512 + (hh*16+c)*8 + 0] * wh * p.proj_b[l*64 + hh*16 + c];
            p.sbf[r] = s;
        }
    } else if (bid < CP+CG){
        // per-graph node stats: batch is SORTED -> binary-search range, coalesced reduce.
        int wv = t>>6, lane = t&63;
        int g = (bid-CP)*4 + wv;         // 0..NG-1
        int lo = 0, hi = p.N;
        while (lo < hi){ int mid = (lo+hi)>>1; if (p.batch[mid] < g) lo = mid+1; else hi = mid; }
        int s0 = lo;
        hi = p.N;
        while (lo < hi){ int mid = (lo+hi)>>1; if (p.batch[mid] < g+1) lo = mid+1; else hi = mid; }
        int s1 = lo;
        float sx=0.f, sy=0.f, sz=0.f;
        for (int i=s0+lane; i<s1; i+=64){
            sx += p.pos[i*3+0]; sy += p.pos[i*3+1]; sz += p.pos[i*3+2];
        }
        #pragma unroll
        for (int off=1; off<64; off<<=1){
            sx += __shfl_xor(sx,off,64);
            sy += __shfl_xor(sy,off,64);
            sz += __shfl_xor(sz,off,64);
        }
        if (lane==0){
            p.possum[g*3+0]=sx; p.possum[g*3+1]=sy; p.possum[g*3+2]=sz;
            p.pcnt[g] = (float)(s1-s0);
        }
    } else if (bid < CP+CG+CT){
        // distance table: one wave per entry, lane = hidden channel
        int wv = t>>6, lane = t&63;
        int i = (bid-CP-CG)*4 + wv;
        if (i > TABN) return;
        float d = (float)i * (16.0f/TABN);
        float t0 = d * (19.0f/10.0f);
        float hv = p.eb1[lane];
        #pragma unroll
        for (int k=0;k<NRBF;k++){
            float a = t0 - (float)k;
            hv += __expf(-0.5f*a*a) * p.ew1[lane*NRBF+k];
        }
        float act = hv/(1.0f+__expf(-hv));
        float p0 = act*p.ew2[0*HID+lane];
        float p1 = act*p.ew2[1*HID+lane];
        float p2 = act*p.ew2[2*HID+lane];
        float p3 = act*p.ew2[3*HID+lane];
        #pragma unroll
        for (int off=1; off<64; off<<=1){
            p0 += __shfl_xor(p0,off,64);
            p1 += __shfl_xor(p1,off,64);
            p2 += __shfl_xor(p2,off,64);
            p3 += __shfl_xor(p3,off,64);
        }
        if (lane==0){
            *(float4*)&p.tab[(size_t)i*4] = make_float4(p0+p.eb2[0], p1+p.eb2[1],
                                                        p2+p.eb2[2], p3+p.eb2[3]);
        }
    } else {
        // atom embedding table: one wave per atom type; lane = out channel
        int wv = t>>6, lane = t&63;
        int za = (bid-CP-CG-CT)*4 + wv;
        if (za >= NATOM) return;
        float accv = p.inproj_b[lane];
        for (int i=0;i<HID;i++)
            accv += p.atom_w[(size_t)za*HID + i] * p.inproj_w[lane*65 + i];
        p.embT[(size_t)za*HID + lane] = accv;
    }
}

// ---------------- proj math body (A-frags supplied by caller) ----------------
__device__ __forceinline__ void proj_core(const P& p, int pl, int n0, int nt, int lane,
        const short8* afr, bool rows16,
        unsigned short* zout, float* ssout, float* sdout){
    const unsigned short* WTl = p.WTbf + (size_t)pl*4*64*64;
    const float* pbl = p.proj_b + pl*HID;
    const float* a_src_l = p.a_src + pl*512;
    const float* a_dst_l = p.a_dst + pl*512;
    const float* w_src_l = p.w_src + pl*16;
    const float* w_dst_l = p.w_dst + pl*16;
    const float* sb_l = p.sbf + pl*8;
    int m = lane&15, quad = lane>>4;
    int o = nt*16 + m;
    float cs[4][2][4];
    float pss[4], psd[4];
    #pragma unroll
    for (int r=0;r<4;r++){ pss[r]=0.f; psd[r]=0.f; }
    #pragma unroll
    for (int bp=0; bp<4; bp++){
        const int b0 = 2*bp, b1 = b0+1;
        const int g0 = gradeOf(b0), g1 = gradeOf(b1);
        const short8 w00 = *(const short8*)(WTl + (g0*64 + o)*64 + quad*8);
        const short8 w01 = *(const short8*)(WTl + (g0*64 + o)*64 + 32 + quad*8);
        short8 w10, w11;
        if (g1==g0){ w10 = w00; w11 = w01; }
        else {
            w10 = *(const short8*)(WTl + (g1*64 + o)*64 + quad*8);
            w11 = *(const short8*)(WTl + (g1*64 + o)*64 + 32 + quad*8);
        }
        floatx4 c0 = {0.f,0.f,0.f,0.f}, c1 = {0.f,0.f,0.f,0.f};
        c0 = __builtin_amdgcn_mfma_f32_16x16x32_bf16(afr[4*bp+0], w00, c0, 0,0,0);
        c0 = __builtin_amdgcn_mfma_f32_16x16x32_bf16(afr[4*bp+1], w01, c0, 0,0,0);
        c1 = __builtin_amdgcn_mfma_f32_16x16x32_bf16(afr[4*bp+2], w10, c1, 0,0,0);
        c1 = __builtin_amdgcn_mfma_f32_16x16x32_bf16(afr[4*bp+3], w11, c1, 0,0,0);
        float as0 = a_src_l[o*8+b0]*w_src_l[nt*4+g0];
        float as1 = a_src_l[o*8+b1]*w_src_l[nt*4+g1];
        float ad0 = a_dst_l[o*8+b0]*w_dst_l[nt*4+g0];
        float ad1 = a_dst_l[o*8+b1]*w_dst_l[nt*4+g1];
        float bias0 = (bp==0) ? pbl[o] : 0.0f;
        #pragma unroll
        for (int r=0;r<4;r++){
            float v0 = c0[r], v1 = c1[r];
            pss[r] += v0*as0 + v1*as1;
            psd[r] += v0*ad0 + v1*ad1;
            cs[bp][0][r] = v0 + bias0;
            cs[bp][1][r] = v1;
        }
    }
    #pragma unroll
    for (int r=0;r<4;r++){
        int row = quad*4 + r;
        bool rowok = rows16 ? true : (quad==0);
        int nn = n0 + (rows16 ? row : r);
        if (rowok && nn < p.N){
            unsigned short pk[8];
            #pragma unroll
            for (int bp=0;bp<4;bp++){
                pk[2*bp]   = f2bf(cs[bp][0][r]);
                pk[2*bp+1] = f2bf(cs[bp][1][r]);
            }
            *(int4*)(zout + (size_t)nn*CB + o*8) = *(int4*)pk;
        }
    }
    #pragma unroll
    for (int r=0;r<4;r++){
        float vs = pss[r], vd = psd[r];
        #pragma unroll
        for (int off=1; off<16; off<<=1){
            vs += __shfl_xor(vs, off, 64);
            vd += __shfl_xor(vd, off, 64);
        }
        int row = quad*4 + r;
        bool rowok = rows16 ? true : (quad==0);
        int nn = n0 + (rows16 ? row : r);
        if (m==0 && rowok && nn<p.N){
            ssout[nn*4+nt] = vs + sb_l[nt];
            sdout[nn*4+nt] = vd + sb_l[4+nt];
        }
    }
}

// ---------------- k2: edge-lerp+bucket | embed+proj_0 (independent block ranges) ----------------
__global__ __launch_bounds__(256) void k2_kernel(P p){
    __shared__ unsigned short hAl[8*16*HSTRIDE];
    int t = threadIdx.x, wv = t>>6, lane = t&63;
    if ((int)blockIdx.x >= p.Mtiles){
        int e = ((int)blockIdx.x - p.Mtiles)*256 + t;
        if (e >= p.E) return;
        int s = p.ei[e], d = p.ei[p.E+e];
        float dx = p.pos[s*3+0]-p.pos[d*3+0];
        float dy = p.pos[s*3+1]-p.pos[d*3+1];
        float dz = p.pos[s*3+2]-p.pos[d*3+2];
        float dist = sqrtf(dx*dx+dy*dy+dz*dz);
        float idxf = fminf(dist * ((float)TABN/16.0f), (float)(TABN-1));
        int i0 = (int)idxf;
        float fr = idxf - (float)i0;
        float4 f0 = *(const float4*)&p.tab[(size_t)i0*4];
        float4 f1 = *(const float4*)&p.tab[(size_t)(i0+1)*4];
        int slot = atomicAdd(&p.counts[d],1);
        if (slot < CAPB){
            p.bucket[(size_t)d*CAPB + slot] = s;                      // src id, slot order
            int2 epk = make_int2(
                packbf2(f0.x + (f1.x-f0.x)*fr, f0.y + (f1.y-f0.y)*fr),
                packbf2(f0.z + (f1.z-f0.z)*fr, f0.w + (f1.w-f0.w)*fr));
            *(int2*)&p.escb[((size_t)d*CAPB + slot)*2] = epk;         // bf16 x4, slot order
        }
        return;
    }
    int n0 = blockIdx.x*16;
    float wvv = p.inproj_w[lane*65 + 64];   // vec-channel weight: loop-invariant
    for (int k=0;k<4;k++){
        int m = wv*4 + k;
        int n = n0 + m;
        if (n < p.N){
            int zn = p.zidx[n];                                   // wave-uniform
            float acc = p.embT[(size_t)zn*HID + lane];            // precomputed embed (L2-hot)
            int g = p.batch[n];
            float cm = p.pcnt[g]; cm = cm>1.0f?cm:1.0f;
            float px = p.pos[n*3+0]-p.possum[g*3+0]/cm;
            float py = p.pos[n*3+1]-p.possum[g*3+1]/cm;
            float pz = p.pos[n*3+2]-p.possum[g*3+2]/cm;
            unsigned short pk[8];
            pk[0]=f2bf(acc); pk[1]=f2bf(wvv*px); pk[2]=f2bf(wvv*py); pk[3]=f2bf(wvv*pz);
            pk[4]=0; pk[5]=0; pk[6]=0; pk[7]=0;
            *(int4*)(p.hb + (size_t)n*CB + lane*8) = *(int4*)pk;
            #pragma unroll
            for (int b=0;b<8;b++) hAl[(b*16+m)*HSTRIDE + lane] = pk[b];
        } else {
            #pragma unroll
            for (int b=0;b<8;b++) hAl[(b*16+m)*HSTRIDE + lane] = 0;
        }
    }
    __syncthreads();
    int m = lane&15, quad = lane>>4;
    short8 afr[16];
    #pragma unroll
    for (int bp=0;bp<4;bp++){
        int b0=2*bp, b1=b0+1;
        afr[4*bp+0] = *(const short8*)(hAl + (b0*16+m)*HSTRIDE + quad*8);
        afr[4*bp+1] = *(const short8*)(hAl + (b0*16+m)*HSTRIDE + 32 + quad*8);
        afr[4*bp+2] = *(const short8*)(hAl + (b1*16+m)*HSTRIDE + quad*8);
        afr[4*bp+3] = *(const short8*)(hAl + (b1*16+m)*HSTRIDE + 32 + quad*8);
    }
    proj_core(p, 0, n0, wv, lane, afr, true, p.zA, p.ssA, p.sdA);
}

// ---------------- agg helpers ----------------
__device__ __forceinline__ void fmab8(const float* lwv, int h_id, int J,
                                      const int4* zv, float* acc, float& dn){
    #pragma unroll
    for (int i=0;i<8;i++){
        float w = lwv[(J+i)*4 + h_id];
        acc[0] += w*bflo(zv[i].x); acc[1] += w*bfhi(zv[i].x);
        acc[2] += w*bflo(zv[i].y); acc[3] += w*bfhi(zv[i].y);
        acc[4] += w*bflo(zv[i].z); acc[5] += w*bfhi(zv[i].z);
        acc[6] += w*bflo(zv[i].w); acc[7] += w*bfhi(zv[i].w);
        dn += w;
    }
}

// ---------------- agg_l: 1 wave = 1 node; batch-0 issued before softmax; bf16 residual ----------------
__global__ __launch_bounds__(256) void agg_kernel(P p, int l,
        const unsigned short* __restrict__ zin, const float* __restrict__ ssin,
        const float* __restrict__ sdin, int last){
    __shared__ float lw[4][256];
    int wv = threadIdx.x>>6, lane = threadIdx.x&63;
    int n = blockIdx.x*4 + wv;
    if (n >= p.N) return;
    float* lwv = lw[wv];
    // residual (bf16 hb row) issued early; consumed only in epilogue
    int4 hres = *((const int4*)(p.hb + (size_t)n*CB) + lane);
    float4 sdl = *(const float4*)&sdin[n*4];
    int deg = min(p.counts[n], CAPB);
    int h_id = lane>>4;
    const int* bs = p.bucket + (size_t)n*CAPB;
    int s = 0;
    float l0=-1e30f,l1=-1e30f,l2=-1e30f,l3=-1e30f;
    if (lane < deg){
        s = bs[lane];                                              // coalesced, slot order
        int2 ev = *((const int2*)p.escb + ((size_t)n*CAPB + lane)); // coalesced, bf16 x4
        float4 sv  = *(const float4*)&ssin[s*4];                   // 16B gather, L2-hot
        l0 = sv.x+sdl.x+bflo(ev.x); l0=(l0>=0.f)?l0:0.2f*l0;
        l1 = sv.y+sdl.y+bfhi(ev.x); l1=(l1>=0.f)?l1:0.2f*l1;
        l2 = sv.z+sdl.z+bflo(ev.y); l2=(l2>=0.f)?l2:0.2f*l2;
        l3 = sv.w+sdl.w+bfhi(ev.y); l3=(l3>=0.f)?l3:0.2f*l3;
    }
    int bc = (deg+7)>>3;
    int4 zv[8];
    // issue batch 0 BEFORE the softmax shuffle chain: loads depend only on s
    if (bc>0){
        #pragma unroll
        for (int i=0;i<8;i++){
            int sb = __builtin_amdgcn_readlane(s, i);
            zv[i] = *((const int4*)(zin + (size_t)(unsigned)sb*CB) + lane);
        }
    }
    float m0=l0,m1=l1,m2=l2,m3=l3;
    #pragma unroll
    for (int off=1; off<64; off<<=1){
        m0=fmaxf(m0,__shfl_xor(m0,off,64));
        m1=fmaxf(m1,__shfl_xor(m1,off,64));
        m2=fmaxf(m2,__shfl_xor(m2,off,64));
        m3=fmaxf(m3,__shfl_xor(m3,off,64));
    }
    // lanes >= deg: l = -1e30 -> exp(l-m) = 0 (deg>0)
    *(float4*)&lwv[lane*4] = make_float4(__expf(l0-m0),__expf(l1-m1),
                                         __expf(l2-m2),__expf(l3-m3));
    float acc[8];
    #pragma unroll
    for (int k=0;k<8;k++) acc[k]=0.f;
    float dn = 0.f;
    if (bc>0) fmab8(lwv, h_id, 0, zv, acc, dn);
    for (int j=8; j<bc*8; j+=8){
        #pragma unroll
        for (int i=0;i<8;i++){
            int sb = __builtin_amdgcn_readlane(s, j+i);
            zv[i] = *((const int4*)(zin + (size_t)(unsigned)sb*CB) + lane);
        }
        fmab8(lwv, h_id, j, zv, acc, dn);
    }
    float inv = 1.0f/(dn + 1e-16f);
    float x[8];
    #pragma unroll
    for (int k=0;k<8;k++) x[k] = acc[k]*inv;
    const float* silu_a_l = p.silu_a + l*HID*4;
    const float* silu_b_l = p.silu_b + l*HID*4;
    float4 sa = *(const float4*)&silu_a_l[lane*4];
    float4 sb = *(const float4*)&silu_b_l[lane*4];
    float n1 = x[1]*x[1]+x[2]*x[2]+x[3]*x[3];
    float n2 = x[4]*x[4]+x[5]*x[5]+x[6]*x[6];
    float n3 = x[7]*x[7];
    float g0 = 1.0f/(1.0f+__expf(-(sa.x*x[0]+sb.x)));
    float g1 = 1.0f/(1.0f+__expf(-(sa.y*n1+sb.y)));
    float g2 = 1.0f/(1.0f+__expf(-(sa.z*n2+sb.z)));
    float g3 = 1.0f/(1.0f+__expf(-(sa.w*n3+sb.w)));
    float val[8];
    val[0]=g0*x[0]+bflo(hres.x); val[1]=g1*x[1]+bfhi(hres.x);
    val[2]=g1*x[2]+bflo(hres.y); val[3]=g1*x[3]+bfhi(hres.y);
    val[4]=g2*x[4]+bflo(hres.z); val[5]=g2*x[5]+bfhi(hres.z);
    val[6]=g2*x[6]+bflo(hres.w); val[7]=g3*x[7]+bfhi(hres.w);
    float ssq=0.f;
    #pragma unroll
    for (int k=0;k<8;k++) ssq += val[k]*val[k];
    float nr = sqrtf(ssq);
    #pragma unroll
    for (int off=1; off<64; off<<=1) nr += __shfl_xor(nr, off, 64);
    float mean = nr*(1.0f/64.0f) + 1e-6f;
    float scale = p.ln_a[l*HID + lane]/mean;
    float outv[8];
    #pragma unroll
    for (int k=0;k<8;k++) outv[k] = scale*val[k];
    if (!last){
        unsigned short pk[8];
        #pragma unroll
        for (int k=0;k<8;k++) pk[k] = f2bf(outv[k]);
        *(int4*)(p.hb + (size_t)n*CB + lane*8) = *(int4*)pk;   // bf16 state for proj + residual
    } else {
        // prepool is linear: accumulate scalar-blade sum per graph; matvec deferred to final
        atomicAdd(&p.gbuf[p.batch[n]*HID + lane], outv[0]);
    }
}

// ---------------- proj_pl: dense MFMA tiles over hb (bf16), 32 nodes/block -> z, ss, sd ----------------
__global__ __launch_bounds__(512) void proj_kernel(P p, int pl,
        unsigned short* zout, float* ssout, float* sdout){
    __shared__ unsigned short hAl[2][8*16*HSTRIDE];
    int t = threadIdx.x, wv = t>>6, lane = t&63;
    int nb = blockIdx.x*32;
    for (int k=0;k<4;k++){
        int m2 = wv*4 + k;              // row 0..31
        int tile = m2>>4, mr = m2&15;
        int n = nb + m2;
        if (n < p.N){
            int4 hv = *((const int4*)(p.hb + (size_t)n*CB) + lane);  // 16B: 8 bf16 blades of chan=lane
            unsigned short* pk = (unsigned short*)&hv;
            #pragma unroll
            for (int b=0;b<8;b++) hAl[tile][(b*16+mr)*HSTRIDE + lane] = pk[b];
        } else {
            #pragma unroll
            for (int b=0;b<8;b++) hAl[tile][(b*16+mr)*HSTRIDE + lane] = 0;
        }
    }
    __syncthreads();
    int tile = wv>>2, nt = wv&3;
    int n0 = nb + tile*16;
    const unsigned short* hT = hAl[tile];
    int m = lane&15, quad = lane>>4;
    short8 afr[16];
    #pragma unroll
    for (int bp=0;bp<4;bp++){
        int b0=2*bp, b1=b0+1;
        afr[4*bp+0] = *(const short8*)(hT + (b0*16+m)*HSTRIDE + quad*8);
        afr[4*bp+1] = *(const short8*)(hT + (b0*16+m)*HSTRIDE + 32 + quad*8);
        afr[4*bp+2] = *(const short8*)(hT + (b1*16+m)*HSTRIDE + quad*8);
        afr[4*bp+3] = *(const short8*)(hT + (b1*16+m)*HSTRIDE + 32 + quad*8);
    }
    proj_core(p, pl, n0, nt, lane, afr, true, zout, ssout, sdout);
}

// ---------------- final readout: gsc = cnt*ppb + W0^T gsum; out = MLP(gsc) ----------------
__global__ void final_kernel(P p){
    int gid = blockIdx.x; int o = threadIdx.x;  // 64 threads = 1 wave
    float gs = p.gbuf[gid*HID + o];             // sum of scalar-blade x0 over graph nodes
    float cnt = p.pcnt[gid];
    float gsc = cnt * p.ppb[o];
    for (int i=0;i<HID;i++) gsc += __shfl(gs, i, 64) * p.ppw0T[i*HID + o];
    float a = p.pb1[o];
    for (int i=0;i<HID;i++) a += __shfl(gsc, i, 64) * p.w1T[i*HID + o];
    float act = a/(1.0f+__expf(-a));
    float pv = act * p.pw2[o];
    #pragma unroll
    for (int off=1; off<64; off<<=1) pv += __shfl_xor(pv, off, 64);
    if (o==0) p.out[gid] = pv + p.pb2[0];
}

extern "C" void kernel_launch(void* const* d_in, const int* in_sizes, int n_in,
                              void* d_out, int out_size, void* d_ws, size_t ws_size,
                              hipStream_t stream) {
    P p;
    p.pos      = (const float*)d_in[0];
    p.zidx     = (const int*)  d_in[1];
    p.ei       = (const int*)  d_in[2];
    p.batch    = (const int*)  d_in[3];
    p.atom_w   = (const float*)d_in[4];
    p.inproj_w = (const float*)d_in[5];
    p.inproj_b = (const float*)d_in[6];
    p.ew1      = (const float*)d_in[7];
    p.eb1      = (const float*)d_in[8];
    p.ew2      = (const float*)d_in[9];
    p.eb2      = (const float*)d_in[10];
    p.proj_w   = (const float*)d_in[11];
    p.proj_b   = (const float*)d_in[12];
    p.a_src    = (const float*)d_in[13];
    p.a_dst    = (const float*)d_in[14];
    p.w_src    = (const float*)d_in[15];
    p.w_dst    = (const float*)d_in[16];
    p.ln_a     = (const float*)d_in[17];
    p.silu_a   = (const float*)d_in[18];
    p.silu_b   = (const float*)d_in[19];
    p.ppw      = (const float*)d_in[20];
    p.ppb      = (const float*)d_in[21];
    p.pw1      = (const float*)d_in[22];
    p.pb1      = (const float*)d_in[23];
    p.pw2      = (const float*)d_in[24];
    p.pb2      = (const float*)d_in[25];
    p.out = (float*)d_out;

    const int N = in_sizes[0]/3;
    const int E = in_sizes[2]/2;
    p.N = N; p.E = E; p.Mtiles = (N+15)/16;

    float* wsf = (float*)d_ws;
    size_t off = 0;
    auto alloc = [&](size_t nelem){ size_t r = off; off += (nelem + 63) & ~(size_t)63; return r; };
    size_t o_counts = alloc(N);          // int  (must be zeroed)
    size_t o_g      = alloc(NG*HID);     // gbuf (must be zeroed)
    size_t zero_end = off;
    size_t o_possum = alloc(NG*3);       // written directly by k1
    size_t o_pcnt   = alloc(NG);         // written directly by k1
    size_t o_bucket = alloc((size_t)N*CAPB);          // int (src ids)
    size_t o_escb   = alloc((size_t)N*CAPB*2);        // int2 per slot (4 bf16)
    size_t o_tab    = alloc((size_t)(TABN+2)*4);
    size_t o_ssA    = alloc((size_t)N*4);
    size_t o_sdA    = alloc((size_t)N*4);
    size_t o_ssB    = alloc((size_t)N*4);
    size_t o_sdB    = alloc((size_t)N*4);
    size_t o_WTbf   = alloc((size_t)LAYERS*4*64*64/2);   // ushort
    size_t o_ppw0T  = alloc(HID*HID);
    size_t o_w1T    = alloc(HID*HID);
    size_t o_sbf    = alloc(2*LAYERS*HEADS);
    size_t o_embT   = alloc((size_t)NATOM*HID);
    size_t o_hb     = alloc((size_t)N*CB/2);             // ushort (bf16 node state)
    size_t o_zA     = alloc((size_t)N*CB/2);             // ushort
    size_t o_zB     = alloc((size_t)N*CB/2);             // ushort

    p.counts = (int*)(wsf + o_counts);
    p.gbuf   = wsf + o_g;
    p.possum = wsf + o_possum;
    p.pcnt   = wsf + o_pcnt;
    p.bucket = (int*)(wsf + o_bucket);
    p.escb   = (int*)(wsf + o_escb);
    p.tab    = wsf + o_tab;
    p.ssA    = wsf + o_ssA;
    p.sdA    = wsf + o_sdA;
    p.ssB    = wsf + o_ssB;
    p.sdB    = wsf + o_sdB;
    p.WTbf   = (unsigned short*)(wsf + o_WTbf);
    p.ppw0T  = wsf + o_ppw0T;
    p.w1T    = wsf + o_w1T;
    p.sbf    = wsf + o_sbf;
    p.embT   = wsf + o_embT;
    p.hb     = (unsigned short*)(wsf + o_hb);
    p.zA     = (unsigned short*)(wsf + o_zA);
    p.zB     = (unsigned short*)(wsf + o_zB);

    hipMemsetAsync(wsf, 0, zero_end*sizeof(float), stream);

    const int PREP_TOTAL = LAYERS*4*64*64 + 2*HID*HID + 2*LAYERS*HEADS;
    const int CP = (PREP_TOTAL+255)/256;
    const int CG = NG/4;
    const int CE = (E+255)/256;
    const int CT = (TABN+1+3)/4;
    const int CEMB = (NATOM+3)/4;

    k1_kernel<<<CP+CG+CT+CEMB, 256, 0, stream>>>(p);
    k2_kernel<<<p.Mtiles + CE, 256, 0, stream>>>(p);    // -> escb/bucket | zA, ssA, sdA, hb

    const int AG = (N+3)/4;
    const int PG = (N+31)/32;
    agg_kernel <<<AG, 256, 0, stream>>>(p, 0, p.zA, p.ssA, p.sdA, 0);
    proj_kernel<<<PG, 512, 0, stream>>>(p, 1, p.zB, p.ssB, p.sdB);
    agg_kernel <<<AG, 256, 0, stream>>>(p, 1, p.zB, p.ssB, p.sdB, 0);
    proj_kernel<<<PG, 512, 0, stream>>>(p, 2, p.zA, p.ssA, p.sdA);
    agg_kernel <<<AG, 256, 0, stream>>>(p, 2, p.zA, p.ssA, p.sdA, 0);
    proj_kernel<<<PG, 512, 0, stream>>>(p, 3, p.zB, p.ssB, p.sdB);
    agg_kernel <<<AG, 256, 0, stream>>>(p, 3, p.zB, p.ssB, p.sdB, 1);

    final_kernel<<<NG, 64, 0, stream>>>(p);
}

// Round 8
// 388.423 us; speedup vs baseline: 1.1537x; 1.0508x over previous
//
#include <hip/hip_runtime.h>
#include <hip/hip_bf16.h>
#include <math.h>

#define HID 64
#define HEADS 4
#define LAYERS 4
#define NRBF 20
#define NG 256
#define CB 512     // HID*8 bf16 elems per z/hb row
#define HSTRIDE 68 // padded channel stride in LDS (bf16 elems)
#define CAPB 64    // per-dst edge bucket capacity (max deg ~37 for Poisson(16), N=20000)
#define TABN 8192  // edge-MLP distance table: [0,16], step 1/512
#define NATOM 100

typedef __attribute__((ext_vector_type(8))) short short8;
typedef __attribute__((ext_vector_type(4))) float floatx4;

__device__ __forceinline__ int gradeOf(int b){ return (b==0)?0:((b<4)?1:((b<7)?2:3)); }
__device__ __forceinline__ unsigned short f2bf(float f){
    __hip_bfloat16 h = __float2bfloat16(f);
    return *(unsigned short*)&h;
}
__device__ __forceinline__ float bflo(int u){ return __uint_as_float(((unsigned)u)<<16); }
__device__ __forceinline__ float bfhi(int u){ return __uint_as_float(((unsigned)u)&0xFFFF0000u); }
__device__ __forceinline__ int packbf2(float a, float b){
    return (int)f2bf(a) | ((int)f2bf(b)<<16);
}

struct P {
    const float *pos; const int *zidx; const int *ei; const int *batch;
    const float *atom_w, *inproj_w, *inproj_b, *ew1, *eb1, *ew2, *eb2;
    const float *proj_w, *proj_b, *a_src, *a_dst, *w_src, *w_dst;
    const float *ln_a, *silu_a, *silu_b, *ppw, *ppb, *pw1, *pb1, *pw2, *pb2;
    float *out;
    int *counts; float *possum; float *pcnt; float *gbuf;
    int *bucket;       // [N][CAPB] src node id per slot
    int *escb;         // [N][CAPB] 2x int: 4 bf16 edge scalars per slot (bucket-slot order)
    float *tab;
    unsigned short *WTbf; float *ppw0T; float *w1T; float *sbf;
    float *embT;       // [NATOM][64] atom -> input_proj scalar channel (bias folded)
    unsigned short *hb;    // bf16 node state (z-row layout); residual + proj input
    unsigned short *zA; unsigned short *zB;
    float *ssA; float *sdA; float *ssB; float *sdB;
    int N, E, Mtiles;
};

// ---------------- k1: weight prep | per-graph stats (no atomics) | distance table | atom-embed ----------------
__global__ __launch_bounds__(256) void k1_kernel(P p){
    const int PREP_TOTAL = LAYERS*4*64*64 + 2*HID*HID + 2*LAYERS*HEADS; // 73760
    const int CP = (PREP_TOTAL+255)/256;
    const int CG = NG/4;                 // 64 blocks: one wave per graph
    const int CT = (TABN+1+3)/4;
    int bid = blockIdx.x, t = threadIdx.x;
    if (bid < CP){
        int idx = bid*256 + t;
        const int szW = LAYERS*4*64*64;
        const int e2 = szW + HID*HID;
        const int e3 = e2 + HID*HID;
        if (idx < szW){
            p.WTbf[idx] = f2bf(p.proj_w[idx]);
        } else if (idx < e2){
            int r = idx - szW; int i = r/HID, o = r%HID;
            p.ppw0T[r] = p.ppw[o*HID + i];
        } else if (idx < e3){
            int r = idx - e2; int i = r/HID, o = r%HID;
            p.w1T[r] = p.pw1[o*HID + i];
        } else if (idx < e3 + 2*LAYERS*HEADS){
            int r = idx - e3;
            int hh = r & 3; int type = (r>>2)&1; int l = r>>3;
            const float* a = type ? p.a_dst : p.a_src;
            const float* w = type ? p.w_dst : p.w_src;
            float wh = w[l*16 + hh*4 + 0];
            float s = 0.f;
            for (int c=0;c<16;c++)
                s += a[l*512 + (hh*16+c)*8 + 0] * wh * p.proj_b[l*64 + hh*16 + c];
            p.sbf[r] = s;
        }
    } else if (bid < CP+CG){
        // per-graph node stats: batch is SORTED -> binary-search range, coalesced reduce.
        int wv = t>>6, lane = t&63;
        int g = (bid-CP)*4 + wv;         // 0..NG-1
        int lo = 0, hi = p.N;
        while (lo < hi){ int mid = (lo+hi)>>1; if (p.batch[mid] < g) lo = mid+1; else hi = mid; }
        int s0 = lo;
        hi = p.N;
        while (lo < hi){ int mid = (lo+hi)>>1; if (p.batch[mid] < g+1) lo = mid+1; else hi = mid; }
        int s1 = lo;
        float sx=0.f, sy=0.f, sz=0.f;
        for (int i=s0+lane; i<s1; i+=64){
            sx += p.pos[i*3+0]; sy += p.pos[i*3+1]; sz += p.pos[i*3+2];
        }
        #pragma unroll
        for (int off=1; off<64; off<<=1){
            sx += __shfl_xor(sx,off,64);
            sy += __shfl_xor(sy,off,64);
            sz += __shfl_xor(sz,off,64);
        }
        if (lane==0){
            p.possum[g*3+0]=sx; p.possum[g*3+1]=sy; p.possum[g*3+2]=sz;
            p.pcnt[g] = (float)(s1-s0);
        }
    } else if (bid < CP+CG+CT){
        // distance table: one wave per entry, lane = hidden channel
        int wv = t>>6, lane = t&63;
        int i = (bid-CP-CG)*4 + wv;
        if (i > TABN) return;
        float d = (float)i * (16.0f/TABN);
        float t0 = d * (19.0f/10.0f);
        float hv = p.eb1[lane];
        #pragma unroll
        for (int k=0;k<NRBF;k++){
            float a = t0 - (float)k;
            hv += __expf(-0.5f*a*a) * p.ew1[lane*NRBF+k];
        }
        float act = hv/(1.0f+__expf(-hv));
        float p0 = act*p.ew2[0*HID+lane];
        float p1 = act*p.ew2[1*HID+lane];
        float p2 = act*p.ew2[2*HID+lane];
        float p3 = act*p.ew2[3*HID+lane];
        #pragma unroll
        for (int off=1; off<64; off<<=1){
            p0 += __shfl_xor(p0,off,64);
            p1 += __shfl_xor(p1,off,64);
            p2 += __shfl_xor(p2,off,64);
            p3 += __shfl_xor(p3,off,64);
        }
        if (lane==0){
            *(float4*)&p.tab[(size_t)i*4] = make_float4(p0+p.eb2[0], p1+p.eb2[1],
                                                        p2+p.eb2[2], p3+p.eb2[3]);
        }
    } else {
        // atom embedding table: one wave per atom type; lane = out channel
        int wv = t>>6, lane = t&63;
        int za = (bid-CP-CG-CT)*4 + wv;
        if (za >= NATOM) return;
        float accv = p.inproj_b[lane];
        for (int i=0;i<HID;i++)
            accv += p.atom_w[(size_t)za*HID + i] * p.inproj_w[lane*65 + i];
        p.embT[(size_t)za*HID + lane] = accv;
    }
}

// ---------------- proj math body: A-frags read from LDS tile (rows (b*16+m)*HSTRIDE) ----------------
__device__ __forceinline__ void proj_core(const P& p, int pl, int n0, int nt, int lane,
        const unsigned short* hAl,
        unsigned short* zout, float* ssout, float* sdout){
    const unsigned short* WTl = p.WTbf + (size_t)pl*4*64*64;
    const float* pbl = p.proj_b + pl*HID;
    const float* a_src_l = p.a_src + pl*512;
    const float* a_dst_l = p.a_dst + pl*512;
    const float* w_src_l = p.w_src + pl*16;
    const float* w_dst_l = p.w_dst + pl*16;
    const float* sb_l = p.sbf + pl*8;
    int m = lane&15, quad = lane>>4;
    int o = nt*16 + m;
    float cs[4][2][4];
    float pss[4], psd[4];
    #pragma unroll
    for (int r=0;r<4;r++){ pss[r]=0.f; psd[r]=0.f; }
    #pragma unroll
    for (int bp=0; bp<4; bp++){
        const int b0 = 2*bp, b1 = b0+1;
        const int g0 = gradeOf(b0), g1 = gradeOf(b1);
        const short8 a0 = *(const short8*)(hAl + (b0*16+m)*HSTRIDE + quad*8);
        const short8 a1 = *(const short8*)(hAl + (b0*16+m)*HSTRIDE + 32 + quad*8);
        const short8 a2 = *(const short8*)(hAl + (b1*16+m)*HSTRIDE + quad*8);
        const short8 a3 = *(const short8*)(hAl + (b1*16+m)*HSTRIDE + 32 + quad*8);
        const short8 w00 = *(const short8*)(WTl + (g0*64 + o)*64 + quad*8);
        const short8 w01 = *(const short8*)(WTl + (g0*64 + o)*64 + 32 + quad*8);
        short8 w10, w11;
        if (g1==g0){ w10 = w00; w11 = w01; }
        else {
            w10 = *(const short8*)(WTl + (g1*64 + o)*64 + quad*8);
            w11 = *(const short8*)(WTl + (g1*64 + o)*64 + 32 + quad*8);
        }
        floatx4 c0 = {0.f,0.f,0.f,0.f}, c1 = {0.f,0.f,0.f,0.f};
        c0 = __builtin_amdgcn_mfma_f32_16x16x32_bf16(a0, w00, c0, 0,0,0);
        c0 = __builtin_amdgcn_mfma_f32_16x16x32_bf16(a1, w01, c0, 0,0,0);
        c1 = __builtin_amdgcn_mfma_f32_16x16x32_bf16(a2, w10, c1, 0,0,0);
        c1 = __builtin_amdgcn_mfma_f32_16x16x32_bf16(a3, w11, c1, 0,0,0);
        float as0 = a_src_l[o*8+b0]*w_src_l[nt*4+g0];
        float as1 = a_src_l[o*8+b1]*w_src_l[nt*4+g1];
        float ad0 = a_dst_l[o*8+b0]*w_dst_l[nt*4+g0];
        float ad1 = a_dst_l[o*8+b1]*w_dst_l[nt*4+g1];
        float bias0 = (bp==0) ? pbl[o] : 0.0f;
        #pragma unroll
        for (int r=0;r<4;r++){
            float v0 = c0[r], v1 = c1[r];
            pss[r] += v0*as0 + v1*as1;
            psd[r] += v0*ad0 + v1*ad1;
            cs[bp][0][r] = v0 + bias0;
            cs[bp][1][r] = v1;
        }
    }
    #pragma unroll
    for (int r=0;r<4;r++){
        int nn = n0 + quad*4 + r;
        if (nn < p.N){
            unsigned short pk[8];
            #pragma unroll
            for (int bp=0;bp<4;bp++){
                pk[2*bp]   = f2bf(cs[bp][0][r]);
                pk[2*bp+1] = f2bf(cs[bp][1][r]);
            }
            *(int4*)(zout + (size_t)nn*CB + o*8) = *(int4*)pk;
        }
    }
    #pragma unroll
    for (int r=0;r<4;r++){
        float vs = pss[r], vd = psd[r];
        #pragma unroll
        for (int off=1; off<16; off<<=1){
            vs += __shfl_xor(vs, off, 64);
            vd += __shfl_xor(vd, off, 64);
        }
        int nn = n0 + quad*4 + r;
        if (m==0 && nn<p.N){
            ssout[nn*4+nt] = vs + sb_l[nt];
            sdout[nn*4+nt] = vd + sb_l[4+nt];
        }
    }
}

// ---------------- k2: edge-lerp+bucket | embed+proj_0 (independent block ranges) ----------------
__global__ __launch_bounds__(256) void k2_kernel(P p){
    __shared__ unsigned short hAl[8*16*HSTRIDE];
    int t = threadIdx.x, wv = t>>6, lane = t&63;
    if ((int)blockIdx.x >= p.Mtiles){
        int e = ((int)blockIdx.x - p.Mtiles)*256 + t;
        if (e >= p.E) return;
        int s = p.ei[e], d = p.ei[p.E+e];
        float dx = p.pos[s*3+0]-p.pos[d*3+0];
        float dy = p.pos[s*3+1]-p.pos[d*3+1];
        float dz = p.pos[s*3+2]-p.pos[d*3+2];
        float dist = sqrtf(dx*dx+dy*dy+dz*dz);
        float idxf = fminf(dist * ((float)TABN/16.0f), (float)(TABN-1));
        int i0 = (int)idxf;
        float fr = idxf - (float)i0;
        float4 f0 = *(const float4*)&p.tab[(size_t)i0*4];
        float4 f1 = *(const float4*)&p.tab[(size_t)(i0+1)*4];
        int slot = atomicAdd(&p.counts[d],1);
        if (slot < CAPB){
            p.bucket[(size_t)d*CAPB + slot] = s;                      // src id, slot order
            int2 epk = make_int2(
                packbf2(f0.x + (f1.x-f0.x)*fr, f0.y + (f1.y-f0.y)*fr),
                packbf2(f0.z + (f1.z-f0.z)*fr, f0.w + (f1.w-f0.w)*fr));
            *(int2*)&p.escb[((size_t)d*CAPB + slot)*2] = epk;         // bf16 x4, slot order
        }
        return;
    }
    int n0 = blockIdx.x*16;
    float wvv = p.inproj_w[lane*65 + 64];   // vec-channel weight: loop-invariant
    for (int k=0;k<4;k++){
        int m = wv*4 + k;
        int n = n0 + m;
        if (n < p.N){
            int zn = p.zidx[n];                                   // wave-uniform
            float acc = p.embT[(size_t)zn*HID + lane];            // precomputed embed (L2-hot)
            int g = p.batch[n];
            float cm = p.pcnt[g]; cm = cm>1.0f?cm:1.0f;
            float px = p.pos[n*3+0]-p.possum[g*3+0]/cm;
            float py = p.pos[n*3+1]-p.possum[g*3+1]/cm;
            float pz = p.pos[n*3+2]-p.possum[g*3+2]/cm;
            unsigned short pk[8];
            pk[0]=f2bf(acc); pk[1]=f2bf(wvv*px); pk[2]=f2bf(wvv*py); pk[3]=f2bf(wvv*pz);
            pk[4]=0; pk[5]=0; pk[6]=0; pk[7]=0;
            *(int4*)(p.hb + (size_t)n*CB + lane*8) = *(int4*)pk;
            #pragma unroll
            for (int b=0;b<8;b++) hAl[(b*16+m)*HSTRIDE + lane] = pk[b];
        } else {
            #pragma unroll
            for (int b=0;b<8;b++) hAl[(b*16+m)*HSTRIDE + lane] = 0;
        }
    }
    __syncthreads();
    proj_core(p, 0, n0, wv, lane, hAl, p.zA, p.ssA, p.sdA);
}

// ---------------- agg helpers ----------------
__device__ __forceinline__ void fmab8(const float* lwv, int h_id, int J,
                                      const int4* zv, float* acc, float& dn){
    #pragma unroll
    for (int i=0;i<8;i++){
        float w = lwv[(J+i)*4 + h_id];
        acc[0] += w*bflo(zv[i].x); acc[1] += w*bfhi(zv[i].x);
        acc[2] += w*bflo(zv[i].y); acc[3] += w*bfhi(zv[i].y);
        acc[4] += w*bflo(zv[i].z); acc[5] += w*bfhi(zv[i].z);
        acc[6] += w*bflo(zv[i].w); acc[7] += w*bfhi(zv[i].w);
        dn += w;
    }
}

// agg body for one node (one wave). Returns outv[8]; writes hb. lwv = per-wave LDS scratch.
__device__ __forceinline__ void agg_node(const P& p, int l, int n, int lane, float* lwv,
        const unsigned short* __restrict__ zin, const float* __restrict__ ssin,
        const float* __restrict__ sdin, float* outv){
    int4 hres = *((const int4*)(p.hb + (size_t)n*CB) + lane);
    float4 sdl = *(const float4*)&sdin[n*4];
    int deg = min(p.counts[n], CAPB);
    int h_id = lane>>4;
    const int* bs = p.bucket + (size_t)n*CAPB;
    int s = 0;
    float l0=-1e30f,l1=-1e30f,l2=-1e30f,l3=-1e30f;
    if (lane < deg){
        s = bs[lane];                                              // coalesced, slot order
        int2 ev = *((const int2*)p.escb + ((size_t)n*CAPB + lane)); // coalesced, bf16 x4
        float4 sv  = *(const float4*)&ssin[s*4];                   // 16B gather, L2-hot
        l0 = sv.x+sdl.x+bflo(ev.x); l0=(l0>=0.f)?l0:0.2f*l0;
        l1 = sv.y+sdl.y+bfhi(ev.x); l1=(l1>=0.f)?l1:0.2f*l1;
        l2 = sv.z+sdl.z+bflo(ev.y); l2=(l2>=0.f)?l2:0.2f*l2;
        l3 = sv.w+sdl.w+bfhi(ev.y); l3=(l3>=0.f)?l3:0.2f*l3;
    }
    int bc = (deg+7)>>3;
    int4 zv[8];
    // issue batch 0 BEFORE the softmax shuffle chain: loads depend only on s
    if (bc>0){
        #pragma unroll
        for (int i=0;i<8;i++){
            int sb = __builtin_amdgcn_readlane(s, i);
            zv[i] = *((const int4*)(zin + (size_t)(unsigned)sb*CB) + lane);
        }
    }
    float m0=l0,m1=l1,m2=l2,m3=l3;
    #pragma unroll
    for (int off=1; off<64; off<<=1){
        m0=fmaxf(m0,__shfl_xor(m0,off,64));
        m1=fmaxf(m1,__shfl_xor(m1,off,64));
        m2=fmaxf(m2,__shfl_xor(m2,off,64));
        m3=fmaxf(m3,__shfl_xor(m3,off,64));
    }
    // lanes >= deg: l = -1e30 -> exp(l-m) = 0 (deg>0)
    *(float4*)&lwv[lane*4] = make_float4(__expf(l0-m0),__expf(l1-m1),
                                         __expf(l2-m2),__expf(l3-m3));
    float acc[8];
    #pragma unroll
    for (int k=0;k<8;k++) acc[k]=0.f;
    float dn = 0.f;
    if (bc>0) fmab8(lwv, h_id, 0, zv, acc, dn);
    for (int j=8; j<bc*8; j+=8){
        #pragma unroll
        for (int i=0;i<8;i++){
            int sb = __builtin_amdgcn_readlane(s, j+i);
            zv[i] = *((const int4*)(zin + (size_t)(unsigned)sb*CB) + lane);
        }
        fmab8(lwv, h_id, j, zv, acc, dn);
    }
    float inv = 1.0f/(dn + 1e-16f);
    float x[8];
    #pragma unroll
    for (int k=0;k<8;k++) x[k] = acc[k]*inv;
    const float* silu_a_l = p.silu_a + l*HID*4;
    const float* silu_b_l = p.silu_b + l*HID*4;
    float4 sa = *(const float4*)&silu_a_l[lane*4];
    float4 sb = *(const float4*)&silu_b_l[lane*4];
    float n1 = x[1]*x[1]+x[2]*x[2]+x[3]*x[3];
    float n2 = x[4]*x[4]+x[5]*x[5]+x[6]*x[6];
    float n3 = x[7]*x[7];
    float g0 = 1.0f/(1.0f+__expf(-(sa.x*x[0]+sb.x)));
    float g1 = 1.0f/(1.0f+__expf(-(sa.y*n1+sb.y)));
    float g2 = 1.0f/(1.0f+__expf(-(sa.z*n2+sb.z)));
    float g3 = 1.0f/(1.0f+__expf(-(sa.w*n3+sb.w)));
    float val[8];
    val[0]=g0*x[0]+bflo(hres.x); val[1]=g1*x[1]+bfhi(hres.x);
    val[2]=g1*x[2]+bflo(hres.y); val[3]=g1*x[3]+bfhi(hres.y);
    val[4]=g2*x[4]+bflo(hres.z); val[5]=g2*x[5]+bfhi(hres.z);
    val[6]=g2*x[6]+bflo(hres.w); val[7]=g3*x[7]+bfhi(hres.w);
    float ssq=0.f;
    #pragma unroll
    for (int k=0;k<8;k++) ssq += val[k]*val[k];
    float nr = sqrtf(ssq);
    #pragma unroll
    for (int off=1; off<64; off<<=1) nr += __shfl_xor(nr, off, 64);
    float mean = nr*(1.0f/64.0f) + 1e-6f;
    float scale = p.ln_a[l*HID + lane]/mean;
    #pragma unroll
    for (int k=0;k<8;k++) outv[k] = scale*val[k];
}

// ---------------- fused agg_l + proj_{l+1}: 16 nodes/block (16 waves) ----------------
__global__ __launch_bounds__(1024) void aggproj_kernel(P p, int l,
        const unsigned short* __restrict__ zin, const float* __restrict__ ssin,
        const float* __restrict__ sdin,
        unsigned short* zout, float* ssout, float* sdout){
    __shared__ float lw[16][256];
    __shared__ unsigned short hAl[8*16*HSTRIDE];
    int wv = threadIdx.x>>6, lane = threadIdx.x&63;
    int n0 = blockIdx.x*16;
    int n = n0 + wv;
    unsigned short pk[8] = {0,0,0,0,0,0,0,0};
    if (n < p.N){
        float outv[8];
        agg_node(p, l, n, lane, lw[wv], zin, ssin, sdin, outv);
        #pragma unroll
        for (int k=0;k<8;k++) pk[k] = f2bf(outv[k]);
        *(int4*)(p.hb + (size_t)n*CB + lane*8) = *(int4*)pk;   // residual for layer l+1
    }
    #pragma unroll
    for (int b=0;b<8;b++) hAl[(b*16+wv)*HSTRIDE + lane] = pk[b];
    __syncthreads();
    if (wv < 4)
        proj_core(p, l+1, n0, wv, lane, hAl, zout, ssout, sdout);
}

// ---------------- agg_3: 1 wave = 1 node; prepool accumulate ----------------
__global__ __launch_bounds__(256) void agg_kernel(P p, int l,
        const unsigned short* __restrict__ zin, const float* __restrict__ ssin,
        const float* __restrict__ sdin){
    __shared__ float lw[4][256];
    int wv = threadIdx.x>>6, lane = threadIdx.x&63;
    int n = blockIdx.x*4 + wv;
    if (n >= p.N) return;
    float outv[8];
    agg_node(p, l, n, lane, lw[wv], zin, ssin, sdin, outv);
    // prepool is linear: accumulate scalar-blade sum per graph; matvec deferred to final
    atomicAdd(&p.gbuf[p.batch[n]*HID + lane], outv[0]);
}

// ---------------- final readout: gsc = cnt*ppb + W0^T gsum; out = MLP(gsc) ----------------
__global__ void final_kernel(P p){
    int gid = blockIdx.x; int o = threadIdx.x;  // 64 threads = 1 wave
    float gs = p.gbuf[gid*HID + o];             // sum of scalar-blade x0 over graph nodes
    float cnt = p.pcnt[gid];
    float gsc = cnt * p.ppb[o];
    for (int i=0;i<HID;i++) gsc += __shfl(gs, i, 64) * p.ppw0T[i*HID + o];
    float a = p.pb1[o];
    for (int i=0;i<HID;i++) a += __shfl(gsc, i, 64) * p.w1T[i*HID + o];
    float act = a/(1.0f+__expf(-a));
    float pv = act * p.pw2[o];
    #pragma unroll
    for (int off=1; off<64; off<<=1) pv += __shfl_xor(pv, off, 64);
    if (o==0) p.out[gid] = pv + p.pb2[0];
}

extern "C" void kernel_launch(void* const* d_in, const int* in_sizes, int n_in,
                              void* d_out, int out_size, void* d_ws, size_t ws_size,
                              hipStream_t stream) {
    P p;
    p.pos      = (const float*)d_in[0];
    p.zidx     = (const int*)  d_in[1];
    p.ei       = (const int*)  d_in[2];
    p.batch    = (const int*)  d_in[3];
    p.atom_w   = (const float*)d_in[4];
    p.inproj_w = (const float*)d_in[5];
    p.inproj_b = (const float*)d_in[6];
    p.ew1      = (const float*)d_in[7];
    p.eb1      = (const float*)d_in[8];
    p.ew2      = (const float*)d_in[9];
    p.eb2      = (const float*)d_in[10];
    p.proj_w   = (const float*)d_in[11];
    p.proj_b   = (const float*)d_in[12];
    p.a_src    = (const float*)d_in[13];
    p.a_dst    = (const float*)d_in[14];
    p.w_src    = (const float*)d_in[15];
    p.w_dst    = (const float*)d_in[16];
    p.ln_a     = (const float*)d_in[17];
    p.silu_a   = (const float*)d_in[18];
    p.silu_b   = (const float*)d_in[19];
    p.ppw      = (const float*)d_in[20];
    p.ppb      = (const float*)d_in[21];
    p.pw1      = (const float*)d_in[22];
    p.pb1      = (const float*)d_in[23];
    p.pw2      = (const float*)d_in[24];
    p.pb2      = (const float*)d_in[25];
    p.out = (float*)d_out;

    const int N = in_sizes[0]/3;
    const int E = in_sizes[2]/2;
    p.N = N; p.E = E; p.Mtiles = (N+15)/16;

    float* wsf = (float*)d_ws;
    size_t off = 0;
    auto alloc = [&](size_t nelem){ size_t r = off; off += (nelem + 63) & ~(size_t)63; return r; };
    size_t o_counts = alloc(N);          // int  (must be zeroed)
    size_t o_g      = alloc(NG*HID);     // gbuf (must be zeroed)
    size_t zero_end = off;
    size_t o_possum = alloc(NG*3);       // written directly by k1
    size_t o_pcnt   = alloc(NG);         // written directly by k1
    size_t o_bucket = alloc((size_t)N*CAPB);          // int (src ids)
    size_t o_escb   = alloc((size_t)N*CAPB*2);        // int2 per slot (4 bf16)
    size_t o_tab    = alloc((size_t)(TABN+2)*4);
    size_t o_ssA    = alloc((size_t)N*4);
    size_t o_sdA    = alloc((size_t)N*4);
    size_t o_ssB    = alloc((size_t)N*4);
    size_t o_sdB    = alloc((size_t)N*4);
    size_t o_WTbf   = alloc((size_t)LAYERS*4*64*64/2);   // ushort
    size_t o_ppw0T  = alloc(HID*HID);
    size_t o_w1T    = alloc(HID*HID);
    size_t o_sbf    = alloc(2*LAYERS*HEADS);
    size_t o_embT   = alloc((size_t)NATOM*HID);
    size_t o_hb     = alloc((size_t)N*CB/2);             // ushort (bf16 node state)
    size_t o_zA     = alloc((size_t)N*CB/2);             // ushort
    size_t o_zB     = alloc((size_t)N*CB/2);             // ushort

    p.counts = (int*)(wsf + o_counts);
    p.gbuf   = wsf + o_g;
    p.possum = wsf + o_possum;
    p.pcnt   = wsf + o_pcnt;
    p.bucket = (int*)(wsf + o_bucket);
    p.escb   = (int*)(wsf + o_escb);
    p.tab    = wsf + o_tab;
    p.ssA    = wsf + o_ssA;
    p.sdA    = wsf + o_sdA;
    p.ssB    = wsf + o_ssB;
    p.sdB    = wsf + o_sdB;
    p.WTbf   = (unsigned short*)(wsf + o_WTbf);
    p.ppw0T  = wsf + o_ppw0T;
    p.w1T    = wsf + o_w1T;
    p.sbf    = wsf + o_sbf;
    p.embT   = wsf + o_embT;
    p.hb     = (unsigned short*)(wsf + o_hb);
    p.zA     = (unsigned short*)(wsf + o_zA);
    p.zB     = (unsigned short*)(wsf + o_zB);

    hipMemsetAsync(wsf, 0, zero_end*sizeof(float), stream);

    const int PREP_TOTAL = LAYERS*4*64*64 + 2*HID*HID + 2*LAYERS*HEADS;
    const int CP = (PREP_TOTAL+255)/256;
    const int CG = NG/4;
    const int CE = (E+255)/256;
    const int CT = (TABN+1+3)/4;
    const int CEMB = (NATOM+3)/4;

    k1_kernel<<<CP+CG+CT+CEMB, 256, 0, stream>>>(p);
    k2_kernel<<<p.Mtiles + CE, 256, 0, stream>>>(p);    // -> escb/bucket | zA, ssA, sdA, hb

    const int FG = (N+15)/16;
    aggproj_kernel<<<FG, 1024, 0, stream>>>(p, 0, p.zA, p.ssA, p.sdA, p.zB, p.ssB, p.sdB);
    aggproj_kernel<<<FG, 1024, 0, stream>>>(p, 1, p.zB, p.ssB, p.sdB, p.zA, p.ssA, p.sdA);
    aggproj_kernel<<<FG, 1024, 0, stream>>>(p, 2, p.zA, p.ssA, p.sdA, p.zB, p.ssB, p.sdB);
    agg_kernel    <<<(N+3)/4, 256, 0, stream>>>(p, 3, p.zB, p.ssB, p.sdB);

    final_kernel<<<NG, 64, 0, stream>>>(p);
}